// Round 7
// baseline (221.557 us; speedup 1.0000x reference)
//
#include <hip/hip_runtime.h>

// LightGCN propagation on MI355X (gfx950).
//   h_{k+1}[r,:] = sum_{e: row[e]==r} val[e] * h_k[col[e],:]   D=32
//   out = (x + h1 + h2 + h3) / 4
//
// Round 7: R6 (8-lane group / float4 / register-accumulate CSR) cut total
// 1135 -> 220 us, confirming the per-edge wave-instruction model. Remaining
// waste: (a) spmm edge records are 8x-redundant scattered broadcasts -- but
// a block's 32 consecutive rows own a CONTIGUOUS edge range (~512 recs),
// so stage it to LDS with coalesced int4 loads and read records via
// broadcast ds_read_b64; (b) bucket_sort read tmp twice -- register-cache
// the records across hist+placement. Build pipeline otherwise unchanged.

#define NN 100000
#define NE 1600000
#define DD 32
#define CHUNK 4096
#define NCHUNK ((NE + CHUNK - 1) / CHUNK)   // 391
#define BROWS 128
#define NBKT ((NN + BROWS - 1) / BROWS)     // 782
#define STAGE 1024                          // staged edge records per spmm block

// ---- pass 1: bucket histogram --------------------------------------------

__global__ __launch_bounds__(1024) void hist_kernel(
    const int* __restrict__ row, int* __restrict__ bucket_tot)
{
    __shared__ int cnt[NBKT];
    const int tid = threadIdx.x;
    const int start = blockIdx.x * CHUNK;
    const int n = min(CHUNK, NE - start);
    for (int k = tid; k < NBKT; k += 1024) cnt[k] = 0;
    __syncthreads();
    #pragma unroll
    for (int k = 0; k < CHUNK / 1024; k++) {
        int j = k * 1024 + tid;
        if (j < n) atomicAdd(&cnt[row[start + j] >> 7], 1);
    }
    __syncthreads();
    for (int k = tid; k < NBKT; k += 1024)
        if (cnt[k]) atomicAdd(&bucket_tot[k], cnt[k]);
}

// ---- pass 2: exclusive scan of 782 bucket totals -> base + cursors -------

__global__ __launch_bounds__(1024) void scan_kernel(
    const int* __restrict__ tot, int* __restrict__ bucketbase,
    int* __restrict__ cursor, int* __restrict__ row_ptr)
{
    const int tid = threadIdx.x;
    int v = (tid < NBKT) ? tot[tid] : 0;
    int lane = tid & 63, w = tid >> 6;          // 16 waves
    int x = v;
    #pragma unroll
    for (int off = 1; off < 64; off <<= 1) {
        int y = __shfl_up(x, off, 64);
        if (lane >= off) x += y;
    }
    __shared__ int wt[16];
    if (lane == 63) wt[w] = x;
    __syncthreads();
    if (w == 0 && lane < 16) {
        int y = wt[lane];
        #pragma unroll
        for (int off = 1; off < 16; off <<= 1) {
            int z = __shfl_up(y, off, 16);
            if ((lane & 15) >= off) y += z;
        }
        wt[lane] = y;                            // inclusive wave totals
    }
    __syncthreads();
    int wo = (w > 0) ? wt[w - 1] : 0;
    int excl = x + wo - v;
    if (tid < NBKT) { bucketbase[tid] = excl; cursor[tid] = excl; }
    if (tid == NBKT) { bucketbase[NBKT] = NE; row_ptr[NN] = NE; }
}

// ---- pass 3: multisplit scatter into bucket-contiguous layout ------------
// record: ((row & 127) << 17) | col   (col < 2^17), val bits in .y

__global__ __launch_bounds__(1024) void scatter_kernel(
    const int* __restrict__ row, const int* __restrict__ col,
    const float* __restrict__ val, int* __restrict__ cursor,
    int2* __restrict__ tmp)
{
    __shared__ int cnt[NBKT];
    __shared__ int gofs[NBKT];
    const int tid = threadIdx.x;
    const int start = blockIdx.x * CHUNK;
    const int n = min(CHUNK, NE - start);
    for (int k = tid; k < NBKT; k += 1024) cnt[k] = 0;
    __syncthreads();

    int rrow[CHUNK / 1024], rank[CHUNK / 1024];
    #pragma unroll
    for (int k = 0; k < CHUNK / 1024; k++) {
        int j = k * 1024 + tid;
        int r = (j < n) ? row[start + j] : -1;
        rrow[k] = r;
        rank[k] = (r >= 0) ? atomicAdd(&cnt[r >> 7], 1) : 0;
    }
    __syncthreads();
    for (int k = tid; k < NBKT; k += 1024)
        if (cnt[k]) gofs[k] = atomicAdd(&cursor[k], cnt[k]);
    __syncthreads();
    #pragma unroll
    for (int k = 0; k < CHUNK / 1024; k++) {
        int j = k * 1024 + tid;
        int r = rrow[k];
        if (r >= 0) {
            int b = r >> 7;
            tmp[gofs[b] + rank[k]] =
                make_int2(((r & 127) << 17) | col[start + j],
                          __float_as_int(val[start + j]));
        }
    }
}

// ---- pass 4: per-bucket row sort -> CSR row_ptr + clean (col,val) --------
// Register-caches up to 2560 records (mean segment 2048, sigma~45) so tmp
// is read once; overflow falls back to a global re-read (never in practice).

__global__ __launch_bounds__(512) void bucket_sort_kernel(
    const int* __restrict__ bucketbase, const int2* __restrict__ tmp,
    int* __restrict__ row_ptr, int2* __restrict__ edges)
{
    __shared__ int cnt[BROWS];
    __shared__ int cur[BROWS];
    __shared__ int wt2[2];
    const int tid = threadIdx.x;
    const int b   = blockIdx.x;
    const int s   = bucketbase[b];
    const int e   = bucketbase[b + 1];

    if (tid < BROWS) cnt[tid] = 0;
    __syncthreads();

    int2 rc[5];
    #pragma unroll
    for (int k = 0; k < 5; k++) {
        int j = s + k * 512 + tid;
        rc[k] = (j < e) ? tmp[j] : make_int2(-1, 0);
        if (rc[k].x >= 0) atomicAdd(&cnt[rc[k].x >> 17], 1);
    }
    for (int j = s + 5 * 512 + tid; j < e; j += 512)       // overflow (rare)
        atomicAdd(&cnt[tmp[j].x >> 17], 1);
    __syncthreads();

    // exclusive scan of 128 counts (waves 0,1)
    int v = 0, x = 0;
    if (tid < BROWS) {
        v = cnt[tid];
        int lane = tid & 63;
        x = v;
        #pragma unroll
        for (int off = 1; off < 64; off <<= 1) {
            int y = __shfl_up(x, off, 64);
            if (lane >= off) x += y;
        }
        if (lane == 63) wt2[tid >> 6] = x;
    }
    __syncthreads();
    if (tid < BROWS) {
        int excl = x + ((tid >> 6) ? wt2[0] : 0) - v;
        cur[tid] = excl;
        int r = b * BROWS + tid;
        if (r < NN) row_ptr[r] = s + excl;
    }
    __syncthreads();

    #pragma unroll
    for (int k = 0; k < 5; k++) {
        if (rc[k].x >= 0) {
            int pos = s + atomicAdd(&cur[rc[k].x >> 17], 1);
            edges[pos] = make_int2(rc[k].x & 0x1FFFF, rc[k].y);
        }
    }
    for (int j = s + 5 * 512 + tid; j < e; j += 512) {     // overflow (rare)
        int2 rec = tmp[j];
        int pos = s + atomicAdd(&cur[rec.x >> 17], 1);
        edges[pos] = make_int2(rec.x & 0x1FFFF, rec.y);
    }
}

// ---- CSR SpMM: 8-lane group per row, float4 lanes, LDS-staged records ----
// Block = 256 thr = 32 consecutive rows; their edge range is contiguous
// (~512 recs avg): coalesced int4 staging -> broadcast ds_read records.
// MODE 0: hout = A x   ; out  = x + hout
// MODE 1: hout = A hin ; out += hout
// MODE 2: out = (out + A hin) * 0.25

template <int MODE>
__global__ __launch_bounds__(256) void spmm_kernel(
    const int* __restrict__ row_ptr, const int2* __restrict__ edges,
    const float4* __restrict__ hin4, float4* __restrict__ hout4,
    const float4* __restrict__ xin4, float4* __restrict__ out4)
{
    __shared__ int4 se4[STAGE / 2 + 1];          // 8.2 KB
    const int2* se = (const int2*)se4;
    const int tid = threadIdx.x;
    const int r0  = blockIdx.x * 32;
    const int g   = r0 + (tid >> 3);             // row (grid covers NN exactly)
    const int t   = tid & 7;                     // float4 lane

    const int s_blk = row_ptr[r0];
    const int e_blk = row_ptr[r0 + 32];
    const int s0     = s_blk & ~1;               // 16-B aligned staging origin
    const int nstage = min(e_blk - s0, STAGE);
    const int4* ep   = (const int4*)(edges + s0);
    const int npairs = (nstage + 1) >> 1;
    for (int p = tid; p < npairs; p += 256) se4[p] = ep[p];
    __syncthreads();

    const int s = row_ptr[g];
    const int e = row_ptr[g + 1];
    const int elds = min(e, s0 + nstage);        // records below this are in LDS

    float4 acc = make_float4(0.f, 0.f, 0.f, 0.f);
    int i = s;
    for (; i + 4 <= elds; i += 4) {              // 4 gathers in flight
        int2 a0 = se[i - s0];
        int2 a1 = se[i + 1 - s0];
        int2 a2 = se[i + 2 - s0];
        int2 a3 = se[i + 3 - s0];
        float4 g0 = hin4[a0.x * 8 + t];
        float4 g1 = hin4[a1.x * 8 + t];
        float4 g2 = hin4[a2.x * 8 + t];
        float4 g3 = hin4[a3.x * 8 + t];
        float v0 = __int_as_float(a0.y), v1 = __int_as_float(a1.y);
        float v2 = __int_as_float(a2.y), v3 = __int_as_float(a3.y);
        acc.x += v0 * g0.x; acc.y += v0 * g0.y; acc.z += v0 * g0.z; acc.w += v0 * g0.w;
        acc.x += v1 * g1.x; acc.y += v1 * g1.y; acc.z += v1 * g1.z; acc.w += v1 * g1.w;
        acc.x += v2 * g2.x; acc.y += v2 * g2.y; acc.z += v2 * g2.z; acc.w += v2 * g2.w;
        acc.x += v3 * g3.x; acc.y += v3 * g3.y; acc.z += v3 * g3.z; acc.w += v3 * g3.w;
    }
    for (; i < elds; ++i) {
        int2 a0 = se[i - s0];
        float4 g0 = hin4[a0.x * 8 + t];
        float v0 = __int_as_float(a0.y);
        acc.x += v0 * g0.x; acc.y += v0 * g0.y; acc.z += v0 * g0.z; acc.w += v0 * g0.w;
    }
    for (; i < e; ++i) {                         // overflow (rare): global
        int2 a0 = edges[i];
        float4 g0 = hin4[a0.x * 8 + t];
        float v0 = __int_as_float(a0.y);
        acc.x += v0 * g0.x; acc.y += v0 * g0.y; acc.z += v0 * g0.z; acc.w += v0 * g0.w;
    }

    const int o = g * 8 + t;
    if (MODE == 0) {
        hout4[o] = acc;
        float4 xv = xin4[o];
        out4[o] = make_float4(xv.x + acc.x, xv.y + acc.y, xv.z + acc.z, xv.w + acc.w);
    } else if (MODE == 1) {
        hout4[o] = acc;
        float4 ov = out4[o];
        out4[o] = make_float4(ov.x + acc.x, ov.y + acc.y, ov.z + acc.z, ov.w + acc.w);
    } else {
        float4 ov = out4[o];
        out4[o] = make_float4((ov.x + acc.x) * 0.25f, (ov.y + acc.y) * 0.25f,
                              (ov.z + acc.z) * 0.25f, (ov.w + acc.w) * 0.25f);
    }
}

// ---- launch ---------------------------------------------------------------

extern "C" void kernel_launch(void* const* d_in, const int* in_sizes, int n_in,
                              void* d_out, int out_size, void* d_ws, size_t ws_size,
                              hipStream_t stream) {
    const int*   edge_row = (const int*)d_in[0];
    const int*   edge_col = (const int*)d_in[1];
    const float* edge_val = (const float*)d_in[2];
    const float* x        = (const float*)d_in[3];
    float* out = (float*)d_out;

    char* ws = (char*)d_ws;
    int*  bucket_tot = (int*)ws;                          ws += 4096;
    int*  bucketbase = (int*)ws;                          ws += 4096;
    int*  cursor     = (int*)ws;                          ws += 4096;
    int*  row_ptr    = (int*)ws;                          ws += ((size_t)(NN + 1) * 4 + 511) & ~511ull;
    int2* tmp        = (int2*)ws;                         ws += (size_t)NE * 8 + 64;  // 12.8 MB (+int4 slack)
    int2* edges      = (int2*)ws;                         ws += (size_t)NE * 8 + 64;  // 12.8 MB (+int4 slack)
    float* h0        = (float*)ws;                        ws += (size_t)NN * DD * 4;
    float* h1        = (float*)ws;

    hipMemsetAsync(bucket_tot, 0, NBKT * sizeof(int), stream);
    hist_kernel       <<<NCHUNK, 1024, 0, stream>>>(edge_row, bucket_tot);
    scan_kernel       <<<1, 1024, 0, stream>>>(bucket_tot, bucketbase, cursor, row_ptr);
    scatter_kernel    <<<NCHUNK, 1024, 0, stream>>>(edge_row, edge_col, edge_val,
                                                    cursor, tmp);
    bucket_sort_kernel<<<NBKT, 512, 0, stream>>>(bucketbase, tmp, row_ptr, edges);

    dim3 sp_grid(NN / 32);   // 3125 blocks, 8 lanes/row, 32 rows/block
    spmm_kernel<0><<<sp_grid, 256, 0, stream>>>(row_ptr, edges,
        (const float4*)x,  (float4*)h0, (const float4*)x, (float4*)out);
    spmm_kernel<1><<<sp_grid, 256, 0, stream>>>(row_ptr, edges,
        (const float4*)h0, (float4*)h1, (const float4*)x, (float4*)out);
    spmm_kernel<2><<<sp_grid, 256, 0, stream>>>(row_ptr, edges,
        (const float4*)h1, (float4*)h0, (const float4*)x, (float4*)out);
}